// Round 1
// baseline (1386.695 us; speedup 1.0000x reference)
//
#include <hip/hip_runtime.h>

#define T_STEPS 500
#define N_NEUR  256
#define N_IN    256
#define N_BATCH 128

// ---------------------------------------------------------------------------
// Kernel 1: XW = X @ W_in   (M=64000, K=256, N=256), fp32 vector-ALU GEMM.
// Tile: 128(M) x 64(N), BK=16, 256 threads, 8x4 acc per thread.
// Accumulation is strictly ascending in k (single accumulator per element).
// ---------------------------------------------------------------------------
__global__ __launch_bounds__(256) void xw_gemm_kernel(
    const float* __restrict__ A,   // [M,256]
    const float* __restrict__ W,   // [256,256]
    float* __restrict__ C)         // [M,256]
{
    __shared__ float As[16][129];  // transposed A tile, +1 pad
    __shared__ float Bs[16][68];   // B tile, +4 pad (keeps float4 alignment)
    const int tid = threadIdx.x;
    const int bm  = blockIdx.x;    // 0..499
    const int bn  = blockIdx.y;    // 0..3
    const int ty  = tid >> 4;      // 0..15
    const int tx  = tid & 15;      // 0..15
    const int arow  = tid >> 1;        // 0..127
    const int akoff = (tid & 1) * 8;   // 0 or 8
    const int brow  = tid >> 4;        // 0..15
    const int bcol  = (tid & 15) * 4;  // 0..60
    const float* Ab = A + (size_t)bm * 128 * 256;

    float acc[8][4];
#pragma unroll
    for (int i = 0; i < 8; ++i)
#pragma unroll
        for (int j = 0; j < 4; ++j) acc[i][j] = 0.f;

    for (int k0 = 0; k0 < 256; k0 += 16) {
        float4 av0 = *(const float4*)(Ab + (size_t)arow * 256 + k0 + akoff);
        float4 av1 = *(const float4*)(Ab + (size_t)arow * 256 + k0 + akoff + 4);
        float4 bv  = *(const float4*)(W + (size_t)(k0 + brow) * 256 + bn * 64 + bcol);
        __syncthreads();
        As[akoff + 0][arow] = av0.x; As[akoff + 1][arow] = av0.y;
        As[akoff + 2][arow] = av0.z; As[akoff + 3][arow] = av0.w;
        As[akoff + 4][arow] = av1.x; As[akoff + 5][arow] = av1.y;
        As[akoff + 6][arow] = av1.z; As[akoff + 7][arow] = av1.w;
        *(float4*)&Bs[brow][bcol] = bv;
        __syncthreads();
#pragma unroll
        for (int kk = 0; kk < 16; ++kk) {
            float a[8], b[4];
#pragma unroll
            for (int i = 0; i < 8; ++i) a[i] = As[kk][ty * 8 + i];
#pragma unroll
            for (int j = 0; j < 4; ++j) b[j] = Bs[kk][tx * 4 + j];
#pragma unroll
            for (int i = 0; i < 8; ++i)
#pragma unroll
                for (int j = 0; j < 4; ++j)
                    acc[i][j] += a[i] * b[j];
        }
    }
    const int crow = bm * 128 + ty * 8;
    const int ccol = bn * 64 + tx * 4;
#pragma unroll
    for (int i = 0; i < 8; ++i) {
        float4 v = make_float4(acc[i][0], acc[i][1], acc[i][2], acc[i][3]);
        *(float4*)(C + (size_t)(crow + i) * 256 + ccol) = v;
    }
}

// ---------------------------------------------------------------------------
// Kernel 2: the recurrent scan. One workgroup per batch (128 WGs x 256 thr),
// thread n owns neuron n's state in registers. Spikes are binary-sparse:
// per-wave ballot builds an active-row list in LDS; recurrent input gathers
// only active rows of w_rec (L2-resident), with up to 32 loads in flight.
// ---------------------------------------------------------------------------
template <bool USE_XW>
__global__ __launch_bounds__(256) void lsnn_scan_kernel(
    const float* __restrict__ xin,   // USE_XW ? xw [B,T,N] : x [B,T,NI]
    const float* __restrict__ w_in,  // [NI,N]  (only used when !USE_XW)
    const float* __restrict__ w_rec, // [N,N]
    const float* __restrict__ z0, const float* __restrict__ v0,
    const float* __restrict__ a0, const float* __restrict__ lsd0,
    float* __restrict__ out)         // [4,T,B,N]
{
    const int b    = blockIdx.x;
    const int n    = threadIdx.x;
    const int lane = n & 63;
    const int wid  = n >> 6;

    __shared__ int   cnt4[4];
    __shared__ int   act[256];   // active indices, segmented per wave
    __shared__ float xsh[256];   // staged x_t (fallback path only)

    // exp(-1/20) rounded to fp32; decay_a == decay_v since TAU == TAU_ADAPT
    const float dv   = (float)0.9512294245007140018;
    const float omdv = 1.0f - dv;

    const int base_bn = b * N_NEUR + n;
    float z   = z0[base_bn];
    float v   = v0[base_bn];
    float a   = a0[base_bn];
    float lsd = lsd0[base_bn];

    act[n] = 0;  // make padding reads safe/deterministic
    {
        unsigned long long wm = __ballot(z != 0.f);
        if (lane == 0) cnt4[wid] = __popcll(wm);
        if (z != 0.f) {
            int pos = __popcll(wm & ((1ull << lane) - 1ull));
            act[wid * 64 + pos] = n;
        }
        if (!USE_XW) xsh[n] = xin[((size_t)b * T_STEPS) * N_IN + n];
    }
    __syncthreads();

    float x_next = USE_XW ? xin[((size_t)b * T_STEPS) * N_NEUR + n] : 0.f;

    for (int t = 0; t < T_STEPS; ++t) {
        float x_cur = x_next;
        if (USE_XW) {  // prefetch next step's xw row early
            int tn = (t + 1 < T_STEPS) ? t + 1 : t;
            x_next = xin[((size_t)b * T_STEPS + tn) * N_NEUR + n];
        }

        // ---- recurrent gather: sum active rows of w_rec -------------------
        const int cs0 = cnt4[0], cs1 = cnt4[1], cs2 = cnt4[2], cs3 = cnt4[3];
        int mx = max(max(cs0, cs1), max(cs2, cs3));
        float r0 = 0.f, r1 = 0.f, r2 = 0.f, r3 = 0.f;
        for (int i0 = 0; i0 < mx; i0 += 8) {
            float wv[4][8];
            bool  ok[4][8];
#pragma unroll
            for (int s = 0; s < 4; ++s) {
                const int cs = (s == 0) ? cs0 : (s == 1) ? cs1 : (s == 2) ? cs2 : cs3;
#pragma unroll
                for (int j = 0; j < 8; ++j) {
                    int ii = i0 + j;
                    int m  = act[s * 64 + (ii < cs ? ii : 0)] & 255; // clamp: safe addr
                    wv[s][j] = w_rec[m * N_NEUR + n];
                    ok[s][j] = (ii < cs) && (m != n);  // exclude self-connection
                }
            }
#pragma unroll
            for (int j = 0; j < 8; ++j) r0 += ok[0][j] ? wv[0][j] : 0.f;
#pragma unroll
            for (int j = 0; j < 8; ++j) r1 += ok[1][j] ? wv[1][j] : 0.f;
#pragma unroll
            for (int j = 0; j < 8; ++j) r2 += ok[2][j] ? wv[2][j] : 0.f;
#pragma unroll
            for (int j = 0; j < 8; ++j) r3 += ok[3][j] ? wv[3][j] : 0.f;
        }
        float i_rec = ((r0 + r1) + r2) + r3;

        // ---- input current ------------------------------------------------
        float xdot;
        if (USE_XW) {
            xdot = x_cur;
        } else {
            float s = 0.f;
#pragma unroll 8
            for (int m = 0; m < N_IN; ++m) s += xsh[m] * w_in[m * N_NEUR + n];
            xdot = s;
        }
        float i_in = xdot + i_rec;  // INTERNAL_CURRENT == 0

        // ---- neuron dynamics (matches reference step exactly) -------------
        float new_a = dv * a + omdv * z;
        float thr   = 0.03f + new_a * 1.8f;
        float new_v = dv * v + omdv * i_in - thr * z;   // i_reset = -thr*old_z
        float v_sc  = (new_v - thr) / thr;
        float zs    = (v_sc > 0.f) ? 1.f : 0.f;
        zs          = (lsd >= 2.0f) ? zs : 0.f;         // refractory mask
        float new_lsd = (lsd + 1.f) * (1.f - zs);

        // ---- emit (z, v, thr, v_sc) -> [4,T,B,N] --------------------------
        const size_t PL = (size_t)T_STEPS * N_BATCH * N_NEUR;
        size_t o = (size_t)t * (N_BATCH * N_NEUR) + (size_t)b * N_NEUR + n;
        out[o]          = zs;
        out[o + PL]     = new_v;
        out[o + 2 * PL] = thr;
        out[o + 3 * PL] = v_sc;

        v = new_v; a = new_a; lsd = new_lsd; z = zs;

        __syncthreads();  // all lanes done reading act/cnt4/xsh of step t
        unsigned long long wm = __ballot(zs != 0.f);
        if (lane == 0) cnt4[wid] = __popcll(wm);
        if (zs != 0.f) {
            int pos = __popcll(wm & ((1ull << lane) - 1ull));
            act[wid * 64 + pos] = n;
        }
        if (!USE_XW && (t + 1 < T_STEPS))
            xsh[n] = xin[((size_t)b * T_STEPS + t + 1) * N_IN + n];
        __syncthreads();
    }
}

// ---------------------------------------------------------------------------
extern "C" void kernel_launch(void* const* d_in, const int* in_sizes, int n_in,
                              void* d_out, int out_size, void* d_ws, size_t ws_size,
                              hipStream_t stream) {
    const float* x     = (const float*)d_in[0];
    const float* w_in  = (const float*)d_in[1];
    const float* w_rec = (const float*)d_in[2];
    const float* z0    = (const float*)d_in[3];
    const float* v0    = (const float*)d_in[4];
    const float* a0    = (const float*)d_in[5];
    const float* lsd0  = (const float*)d_in[6];
    float* out = (float*)d_out;

    const size_t xw_bytes = (size_t)N_BATCH * T_STEPS * N_NEUR * sizeof(float);

    if (ws_size >= xw_bytes) {
        float* xw = (float*)d_ws;
        dim3 grid(500, 4, 1);
        xw_gemm_kernel<<<grid, 256, 0, stream>>>(x, w_in, xw);
        lsnn_scan_kernel<true><<<N_BATCH, 256, 0, stream>>>(
            xw, nullptr, w_rec, z0, v0, a0, lsd0, out);
    } else {
        // Fallback: fused dense x@w_in inside the scan (slow but correct).
        lsnn_scan_kernel<false><<<N_BATCH, 256, 0, stream>>>(
            x, w_in, w_rec, z0, v0, a0, lsd0, out);
    }
}

// Round 3
// 902.969 us; speedup vs baseline: 1.5357x; 1.5357x over previous
//
#include <hip/hip_runtime.h>

#define T_STEPS 500
#define N_NEUR  256
#define N_IN    256
#define N_BATCH 128

// ---------------------------------------------------------------------------
// Kernel 1: XW = X @ W_in   (M=64000, K=256, N=256), fp32 vector-ALU GEMM.
// (unchanged from R1 — known-correct numerics)
// ---------------------------------------------------------------------------
__global__ __launch_bounds__(256) void xw_gemm_kernel(
    const float* __restrict__ A,   // [M,256]
    const float* __restrict__ W,   // [256,256]
    float* __restrict__ C)         // [M,256]
{
    __shared__ float As[16][129];
    __shared__ float Bs[16][68];
    const int tid = threadIdx.x;
    const int bm  = blockIdx.x;
    const int bn  = blockIdx.y;
    const int ty  = tid >> 4;
    const int tx  = tid & 15;
    const int arow  = tid >> 1;
    const int akoff = (tid & 1) * 8;
    const int brow  = tid >> 4;
    const int bcol  = (tid & 15) * 4;
    const float* Ab = A + (size_t)bm * 128 * 256;

    float acc[8][4];
#pragma unroll
    for (int i = 0; i < 8; ++i)
#pragma unroll
        for (int j = 0; j < 4; ++j) acc[i][j] = 0.f;

    for (int k0 = 0; k0 < 256; k0 += 16) {
        float4 av0 = *(const float4*)(Ab + (size_t)arow * 256 + k0 + akoff);
        float4 av1 = *(const float4*)(Ab + (size_t)arow * 256 + k0 + akoff + 4);
        float4 bv  = *(const float4*)(W + (size_t)(k0 + brow) * 256 + bn * 64 + bcol);
        __syncthreads();
        As[akoff + 0][arow] = av0.x; As[akoff + 1][arow] = av0.y;
        As[akoff + 2][arow] = av0.z; As[akoff + 3][arow] = av0.w;
        As[akoff + 4][arow] = av1.x; As[akoff + 5][arow] = av1.y;
        As[akoff + 6][arow] = av1.z; As[akoff + 7][arow] = av1.w;
        *(float4*)&Bs[brow][bcol] = bv;
        __syncthreads();
#pragma unroll
        for (int kk = 0; kk < 16; ++kk) {
            float a[8], b[4];
#pragma unroll
            for (int i = 0; i < 8; ++i) a[i] = As[kk][ty * 8 + i];
#pragma unroll
            for (int j = 0; j < 4; ++j) b[j] = Bs[kk][tx * 4 + j];
#pragma unroll
            for (int i = 0; i < 8; ++i)
#pragma unroll
                for (int j = 0; j < 4; ++j)
                    acc[i][j] += a[i] * b[j];
        }
    }
    const int crow = bm * 128 + ty * 8;
    const int ccol = bn * 64 + tx * 4;
#pragma unroll
    for (int i = 0; i < 8; ++i) {
        float4 v = make_float4(acc[i][0], acc[i][1], acc[i][2], acc[i][3]);
        *(float4*)(C + (size_t)(crow + i) * 256 + ccol) = v;
    }
}

// ---------------------------------------------------------------------------
// Kernel 1b: build wrec_z = w_rec with zeroed diagonal + zero sentinel row 256.
// ---------------------------------------------------------------------------
__global__ void prep_wrec_kernel(const float* __restrict__ w_rec,
                                 float* __restrict__ wz)
{
    int i = blockIdx.x * 256 + threadIdx.x;   // 0 .. 257*256-1
    if (i < 256 * 256) {
        int r = i >> 8, c = i & 255;
        wz[i] = (r == c) ? 0.f : w_rec[i];
    } else {
        wz[i] = 0.f;                           // sentinel row 256
    }
}

// ---------------------------------------------------------------------------
// Kernel 2 (v2): recurrent scan. One WG per batch, thread n = neuron n.
// Active spikes tracked as 4 x u64 ballot masks (double-buffered in LDS, one
// barrier/step). Each thread walks the masks in SCALAR registers, extracting
// 8 indices per wave-mask per iteration -> 32 loads in flight from the
// diag-zeroed w_rec copy; exhausted masks yield sentinel row 256 (zeros), so
// the accumulate is predicate-free. i_rec accumulation order is bit-identical
// to the R1-passing kernel (per-wave partials, ascending index, +0.0 pads).
// ---------------------------------------------------------------------------
__device__ __forceinline__ unsigned long long rfl64(unsigned long long q) {
    unsigned hi = (unsigned)__builtin_amdgcn_readfirstlane((int)(q >> 32));
    unsigned lo = (unsigned)__builtin_amdgcn_readfirstlane((int)(unsigned)q);
    return ((unsigned long long)hi << 32) | (unsigned long long)lo;
}

__global__ __launch_bounds__(256) void lsnn_scan2_kernel(
    const float* __restrict__ xw,    // [B,T,N]
    const float* __restrict__ wz,    // [257,256] diag-zeroed + zero row
    const float* __restrict__ z0, const float* __restrict__ v0,
    const float* __restrict__ a0, const float* __restrict__ lsd0,
    float* __restrict__ out)         // [4,T,B,N]
{
    const int b    = blockIdx.x;
    const int n    = threadIdx.x;
    const int lane = n & 63;
    const int wid  = n >> 6;

    __shared__ unsigned long long msk[2][4];

    const float dv   = (float)0.9512294245007140018;  // exp(-1/20) fp32
    const float omdv = 1.0f - dv;

    const int bn = b * N_NEUR + n;
    float z   = z0[bn];
    float v   = v0[bn];
    float a   = a0[bn];
    float lsd = lsd0[bn];

    {
        unsigned long long wm = __ballot(z != 0.f);
        if (lane == 0) msk[0][wid] = wm;
    }
    __syncthreads();

    float x_next = xw[((size_t)b * T_STEPS) * N_NEUR + n];
    const size_t PL = (size_t)T_STEPS * N_BATCH * N_NEUR;

    for (int t = 0; t < T_STEPS; ++t) {
        float x_cur = x_next;
        {
            int tn = (t + 1 < T_STEPS) ? t + 1 : t;
            x_next = xw[((size_t)b * T_STEPS + tn) * N_NEUR + n];
        }

        const int rb = t & 1;
        // ---- pull the 4 wave masks into scalar registers ------------------
        unsigned long long m0 = rfl64(msk[rb][0]);
        unsigned long long m1 = rfl64(msk[rb][1]);
        unsigned long long m2 = rfl64(msk[rb][2]);
        unsigned long long m3 = rfl64(msk[rb][3]);

        const int c0 = __popcll(m0), c1 = __popcll(m1);
        const int c2 = __popcll(m2), c3 = __popcll(m3);
        const int mx = max(max(c0, c1), max(c2, c3));

        // ---- gather: 32 loads in flight per iteration ---------------------
        float p0 = 0.f, p1 = 0.f, p2 = 0.f, p3 = 0.f;
        for (int i0 = 0; i0 < mx; i0 += 8) {
            int id0[8], id1[8], id2[8], id3[8];
#pragma unroll
            for (int j = 0; j < 8; ++j) {
                id0[j] = m0 ? (__builtin_ctzll(m0) + 0)   : 256;  m0 &= m0 - 1;
                id1[j] = m1 ? (__builtin_ctzll(m1) + 64)  : 256;  m1 &= m1 - 1;
                id2[j] = m2 ? (__builtin_ctzll(m2) + 128) : 256;  m2 &= m2 - 1;
                id3[j] = m3 ? (__builtin_ctzll(m3) + 192) : 256;  m3 &= m3 - 1;
            }
            float w0[8], w1[8], w2[8], w3[8];
#pragma unroll
            for (int j = 0; j < 8; ++j) {
                w0[j] = wz[id0[j] * N_NEUR + n];
                w1[j] = wz[id1[j] * N_NEUR + n];
                w2[j] = wz[id2[j] * N_NEUR + n];
                w3[j] = wz[id3[j] * N_NEUR + n];
            }
#pragma unroll
            for (int j = 0; j < 8; ++j) {
                p0 += w0[j]; p1 += w1[j]; p2 += w2[j]; p3 += w3[j];
            }
        }
        float i_rec = ((p0 + p1) + p2) + p3;

        // ---- neuron dynamics (matches reference step exactly) -------------
        float i_in  = x_cur + i_rec;              // INTERNAL_CURRENT == 0
        float new_a = dv * a + omdv * z;
        float thr   = 0.03f + new_a * 1.8f;
        float new_v = dv * v + omdv * i_in - thr * z;
        float v_sc  = (new_v - thr) / thr;
        float zs    = (v_sc > 0.f) ? 1.f : 0.f;
        zs          = (lsd >= 2.0f) ? zs : 0.f;
        float new_lsd = (lsd + 1.f) * (1.f - zs);

        // ---- emit (z, v, thr, v_sc) -> [4,T,B,N], streaming stores --------
        size_t o = (size_t)t * (N_BATCH * N_NEUR) + (size_t)b * N_NEUR + n;
        __builtin_nontemporal_store(zs,    out + o);
        __builtin_nontemporal_store(new_v, out + o + PL);
        __builtin_nontemporal_store(thr,   out + o + 2 * PL);
        __builtin_nontemporal_store(v_sc,  out + o + 3 * PL);

        v = new_v; a = new_a; lsd = new_lsd; z = zs;

        // ---- publish new masks to the other buffer; ONE barrier/step ------
        {
            unsigned long long wm = __ballot(zs != 0.f);
            if (lane == 0) msk[rb ^ 1][wid] = wm;
        }
        __syncthreads();
    }
}

// ---------------------------------------------------------------------------
// Fallback scan (R1 version) — used only if ws_size is too small.
// ---------------------------------------------------------------------------
template <bool USE_XW>
__global__ __launch_bounds__(256) void lsnn_scan_kernel(
    const float* __restrict__ xin,
    const float* __restrict__ w_in,
    const float* __restrict__ w_rec,
    const float* __restrict__ z0, const float* __restrict__ v0,
    const float* __restrict__ a0, const float* __restrict__ lsd0,
    float* __restrict__ out)
{
    const int b    = blockIdx.x;
    const int n    = threadIdx.x;
    const int lane = n & 63;
    const int wid  = n >> 6;

    __shared__ int   cnt4[4];
    __shared__ int   act[256];
    __shared__ float xsh[256];

    const float dv   = (float)0.9512294245007140018;
    const float omdv = 1.0f - dv;

    const int base_bn = b * N_NEUR + n;
    float z   = z0[base_bn];
    float v   = v0[base_bn];
    float a   = a0[base_bn];
    float lsd = lsd0[base_bn];

    act[n] = 0;
    {
        unsigned long long wm = __ballot(z != 0.f);
        if (lane == 0) cnt4[wid] = __popcll(wm);
        if (z != 0.f) {
            int pos = __popcll(wm & ((1ull << lane) - 1ull));
            act[wid * 64 + pos] = n;
        }
        if (!USE_XW) xsh[n] = xin[((size_t)b * T_STEPS) * N_IN + n];
    }
    __syncthreads();

    float x_next = USE_XW ? xin[((size_t)b * T_STEPS) * N_NEUR + n] : 0.f;

    for (int t = 0; t < T_STEPS; ++t) {
        float x_cur = x_next;
        if (USE_XW) {
            int tn = (t + 1 < T_STEPS) ? t + 1 : t;
            x_next = xin[((size_t)b * T_STEPS + tn) * N_NEUR + n];
        }
        const int cs0 = cnt4[0], cs1 = cnt4[1], cs2 = cnt4[2], cs3 = cnt4[3];
        int mx = max(max(cs0, cs1), max(cs2, cs3));
        float r0 = 0.f, r1 = 0.f, r2 = 0.f, r3 = 0.f;
        for (int i0 = 0; i0 < mx; i0 += 8) {
            float wv[4][8];
            bool  ok[4][8];
#pragma unroll
            for (int s = 0; s < 4; ++s) {
                const int cs = (s == 0) ? cs0 : (s == 1) ? cs1 : (s == 2) ? cs2 : cs3;
#pragma unroll
                for (int j = 0; j < 8; ++j) {
                    int ii = i0 + j;
                    int m  = act[s * 64 + (ii < cs ? ii : 0)] & 255;
                    wv[s][j] = w_rec[m * N_NEUR + n];
                    ok[s][j] = (ii < cs) && (m != n);
                }
            }
#pragma unroll
            for (int j = 0; j < 8; ++j) r0 += ok[0][j] ? wv[0][j] : 0.f;
#pragma unroll
            for (int j = 0; j < 8; ++j) r1 += ok[1][j] ? wv[1][j] : 0.f;
#pragma unroll
            for (int j = 0; j < 8; ++j) r2 += ok[2][j] ? wv[2][j] : 0.f;
#pragma unroll
            for (int j = 0; j < 8; ++j) r3 += ok[3][j] ? wv[3][j] : 0.f;
        }
        float i_rec = ((r0 + r1) + r2) + r3;

        float xdot;
        if (USE_XW) {
            xdot = x_cur;
        } else {
            float s = 0.f;
#pragma unroll 8
            for (int m = 0; m < N_IN; ++m) s += xsh[m] * w_in[m * N_NEUR + n];
            xdot = s;
        }
        float i_in = xdot + i_rec;

        float new_a = dv * a + omdv * z;
        float thr   = 0.03f + new_a * 1.8f;
        float new_v = dv * v + omdv * i_in - thr * z;
        float v_sc  = (new_v - thr) / thr;
        float zs    = (v_sc > 0.f) ? 1.f : 0.f;
        zs          = (lsd >= 2.0f) ? zs : 0.f;
        float new_lsd = (lsd + 1.f) * (1.f - zs);

        const size_t PL = (size_t)T_STEPS * N_BATCH * N_NEUR;
        size_t o = (size_t)t * (N_BATCH * N_NEUR) + (size_t)b * N_NEUR + n;
        out[o]          = zs;
        out[o + PL]     = new_v;
        out[o + 2 * PL] = thr;
        out[o + 3 * PL] = v_sc;

        v = new_v; a = new_a; lsd = new_lsd; z = zs;

        __syncthreads();
        unsigned long long wm = __ballot(zs != 0.f);
        if (lane == 0) cnt4[wid] = __popcll(wm);
        if (zs != 0.f) {
            int pos = __popcll(wm & ((1ull << lane) - 1ull));
            act[wid * 64 + pos] = n;
        }
        if (!USE_XW && (t + 1 < T_STEPS))
            xsh[n] = xin[((size_t)b * T_STEPS + t + 1) * N_IN + n];
        __syncthreads();
    }
}

// ---------------------------------------------------------------------------
extern "C" void kernel_launch(void* const* d_in, const int* in_sizes, int n_in,
                              void* d_out, int out_size, void* d_ws, size_t ws_size,
                              hipStream_t stream) {
    const float* x     = (const float*)d_in[0];
    const float* w_in  = (const float*)d_in[1];
    const float* w_rec = (const float*)d_in[2];
    const float* z0    = (const float*)d_in[3];
    const float* v0    = (const float*)d_in[4];
    const float* a0    = (const float*)d_in[5];
    const float* lsd0  = (const float*)d_in[6];
    float* out = (float*)d_out;

    const size_t xw_bytes = (size_t)N_BATCH * T_STEPS * N_NEUR * sizeof(float);
    const size_t wz_bytes = (size_t)257 * 256 * sizeof(float);

    if (ws_size >= xw_bytes + wz_bytes) {
        float* xw = (float*)d_ws;
        float* wz = (float*)((char*)d_ws + xw_bytes);
        prep_wrec_kernel<<<257, 256, 0, stream>>>(w_rec, wz);
        dim3 grid(500, 4, 1);
        xw_gemm_kernel<<<grid, 256, 0, stream>>>(x, w_in, xw);
        lsnn_scan2_kernel<<<N_BATCH, 256, 0, stream>>>(
            xw, wz, z0, v0, a0, lsd0, out);
    } else if (ws_size >= xw_bytes) {
        float* xw = (float*)d_ws;
        dim3 grid(500, 4, 1);
        xw_gemm_kernel<<<grid, 256, 0, stream>>>(x, w_in, xw);
        lsnn_scan_kernel<true><<<N_BATCH, 256, 0, stream>>>(
            xw, nullptr, w_rec, z0, v0, a0, lsd0, out);
    } else {
        lsnn_scan_kernel<false><<<N_BATCH, 256, 0, stream>>>(
            x, w_in, w_rec, z0, v0, a0, lsd0, out);
    }
}